// Round 1
// baseline (72.586 us; speedup 1.0000x reference)
//
#include <hip/hip_runtime.h>

#define CCH 128
#define HW 3136            // 56*56
#define BATCH 64
#define NPC (BATCH * HW)   // 200704 elements per channel
#define NBINS 2048
#define GROUPS 8           // blocks per channel in stats pass
#define BPG (BATCH / GROUPS)

// workspace layout (bytes):
//   [0, CCH*NBINS*4)                      : uint hist[CCH][NBINS]
//   [HIST_BYTES, HIST_BYTES + 2*CCH*4)    : float sums[2*CCH]  (sum, then sumsq)
//   [.. + 2*CCH*4 .. )                    : float scale_shift[2*CCH]
#define HIST_BYTES (CCH * NBINS * 4)
#define SUMS_OFF   HIST_BYTES
#define SS_OFF     (HIST_BYTES + 2 * CCH * 4)
#define ZERO_BYTES (HIST_BYTES + 2 * CCH * 4)

__global__ __launch_bounds__(256) void rmbn_stats(const float* __restrict__ x,
                                                  unsigned int* __restrict__ hist,
                                                  float* __restrict__ sums) {
    const int blk = blockIdx.x;
    const int c = blk / GROUPS;
    const int g = blk % GROUPS;

    __shared__ unsigned int lh[NBINS];
    for (int i = threadIdx.x; i < NBINS; i += 256) lh[i] = 0;
    __syncthreads();

    float s = 0.f, ss = 0.f;
    for (int bb = 0; bb < BPG; ++bb) {
        const int b = g * BPG + bb;
        const float4* p = (const float4*)(x + (size_t)(b * CCH + c) * HW);
        for (int i = threadIdx.x; i < HW / 4; i += 256) {
            float4 v = p[i];
            float e[4] = {v.x, v.y, v.z, v.w};
#pragma unroll
            for (int j = 0; j < 4; ++j) {
                float vv = e[j];
                s += vv;
                ss = fmaf(vv, vv, ss);
                int bin = (int)fmaf(vv, 128.f, 1024.f);  // (v+8)*NBINS/16
                bin = bin < 0 ? 0 : (bin > NBINS - 1 ? NBINS - 1 : bin);
                atomicAdd(&lh[bin], 1u);
            }
        }
    }
    __syncthreads();

    // flush histogram
    for (int i = threadIdx.x; i < NBINS; i += 256) {
        unsigned int v = lh[i];
        if (v) atomicAdd(&hist[c * NBINS + i], v);
    }

    // block-reduce sum/sumsq
    for (int off = 32; off; off >>= 1) {
        s += __shfl_down(s, off);
        ss += __shfl_down(ss, off);
    }
    __shared__ float ws_s[4], ws_ss[4];
    const int lane = threadIdx.x & 63, wid = threadIdx.x >> 6;
    if (lane == 0) { ws_s[wid] = s; ws_ss[wid] = ss; }
    __syncthreads();
    if (threadIdx.x == 0) {
        float ts = ws_s[0] + ws_s[1] + ws_s[2] + ws_s[3];
        float tss = ws_ss[0] + ws_ss[1] + ws_ss[2] + ws_ss[3];
        atomicAdd(&sums[c], ts);
        atomicAdd(&sums[CCH + c], tss);
    }
}

__global__ __launch_bounds__(256) void rmbn_finalize(const unsigned int* __restrict__ hist,
                                                     const float* __restrict__ sums,
                                                     const float* __restrict__ weight,
                                                     const float* __restrict__ bias,
                                                     const float* __restrict__ smean,
                                                     const float* __restrict__ svar,
                                                     float* __restrict__ scale_shift) {
    const int c = blockIdx.x;
    const int t = threadIdx.x;
    __shared__ unsigned int lh[NBINS];
    __shared__ unsigned int chunk[256];

    const unsigned int* h = hist + c * NBINS;
    unsigned int cs = 0;
    for (int j = 0; j < NBINS / 256; ++j) {
        unsigned int v = h[t + 256 * j];   // coalesced
        lh[t + 256 * j] = v;
    }
    __syncthreads();
    cs = 0;
    for (int j = 0; j < 8; ++j) cs += lh[t * 8 + j];
    chunk[t] = cs;
    __syncthreads();

    if (t == 0) {
        const unsigned int target = (NPC - 1) / 2 + 1;  // rank 100352 (1-indexed)
        unsigned int cum = 0;
        int ch = 0;
        for (int i = 0; i < 256; ++i) {
            if (cum + chunk[i] >= target) { ch = i; break; }
            cum += chunk[i];
        }
        int bin = ch * 8;
        for (int j = 0; j < 8; ++j) {
            unsigned int hv = lh[ch * 8 + j];
            if (cum + hv >= target) { bin = ch * 8 + j; break; }
            cum += hv;
        }
        const unsigned int cnt = lh[bin];
        const unsigned int r = target - cum;  // 1..cnt
        const float width = 16.f / NBINS;
        const float lo = -8.f + bin * width;
        const float m = lo + width * (((float)r - 0.5f) / (float)cnt);

        const float n = (float)NPC;
        const float sum = sums[c], sumsq = sums[CCH + c];
        const float bvar = sumsq / n - 2.f * m * (sum / n) + m * m;
        const float mean = 0.9f * smean[c] + 0.1f * m;
        const float var = 0.9f * svar[c] + 0.1f * bvar;
        const float inv = rsqrtf(var + 1e-5f);
        const float sc = inv * weight[c];
        scale_shift[c] = sc;
        scale_shift[CCH + c] = bias[c] - mean * sc;
    }
}

__global__ __launch_bounds__(256) void rmbn_norm(const float* __restrict__ x,
                                                 const float* __restrict__ ss,
                                                 float* __restrict__ out) {
    const int blk = blockIdx.x;      // B*C blocks, one (b,c) slab each
    const int c = blk % CCH;
    const float sc = ss[c];
    const float sh = ss[CCH + c];
    const size_t base = (size_t)blk * HW;
    const float4* px = (const float4*)(x + base);
    float4* po = (float4*)(out + base);
    for (int i = threadIdx.x; i < HW / 4; i += 256) {
        float4 v = px[i];
        v.x = fmaf(v.x, sc, sh);
        v.y = fmaf(v.y, sc, sh);
        v.z = fmaf(v.z, sc, sh);
        v.w = fmaf(v.w, sc, sh);
        po[i] = v;
    }
}

extern "C" void kernel_launch(void* const* d_in, const int* in_sizes, int n_in,
                              void* d_out, int out_size, void* d_ws, size_t ws_size,
                              hipStream_t stream) {
    const float* x = (const float*)d_in[0];
    const float* weight = (const float*)d_in[1];
    const float* bias = (const float*)d_in[2];
    const float* smean = (const float*)d_in[3];
    const float* svar = (const float*)d_in[4];
    float* out = (float*)d_out;

    unsigned char* ws = (unsigned char*)d_ws;
    unsigned int* hist = (unsigned int*)(ws);
    float* sums = (float*)(ws + SUMS_OFF);
    float* scsh = (float*)(ws + SS_OFF);

    hipMemsetAsync(d_ws, 0, ZERO_BYTES, stream);

    rmbn_stats<<<CCH * GROUPS, 256, 0, stream>>>(x, hist, sums);
    rmbn_finalize<<<CCH, 256, 0, stream>>>(hist, sums, weight, bias, smean, svar, scsh);
    rmbn_norm<<<BATCH * CCH, 256, 0, stream>>>(x, scsh, out);
}

// Round 2
// 65.096 us; speedup vs baseline: 1.1150x; 1.1150x over previous
//
#include <hip/hip_runtime.h>

#define CCH 128
#define HW 3136            // 56*56
#define BATCH 64
#define NPC (BATCH * HW)   // 200704 elements per channel
#define NBINS 2048
#define GROUPS 8           // blocks per channel in stats pass
#define BPG (BATCH / GROUPS)

typedef float f4v __attribute__((ext_vector_type(4)));

// ---------------- path A workspace layout (no memset needed) ----------------
// hist packed u16x2: uint histp[CCH*GROUPS][NBINS/2]      = 4 MB
// float sums[2][CCH*GROUPS]                               = 8 KB
// float scale_shift[2*CCH]                                = 1 KB
#define HISTA_WORDS (CCH * GROUPS * (NBINS / 2))
#define HISTA_BYTES (HISTA_WORDS * 4)
#define SUMSA_OFF   HISTA_BYTES
#define SCSHA_OFF   (SUMSA_OFF + 2 * CCH * GROUPS * 4)
#define NEEDA       (SCSHA_OFF + 2 * CCH * 4)

// ---------------- path B (fallback, needs memset) ----------------
#define HISTB_BYTES (CCH * NBINS * 4)
#define SUMSB_OFF   HISTB_BYTES
#define SCSHB_OFF   (HISTB_BYTES + 2 * CCH * 4)
#define ZEROB_BYTES (HISTB_BYTES + 2 * CCH * 4)

// ============================ PATH A ============================

__global__ __launch_bounds__(256) void rmbn_stats_a(const float* __restrict__ x,
                                                    unsigned int* __restrict__ histp,
                                                    float* __restrict__ sums) {
    const int blk = blockIdx.x;
    const int c = blk / GROUPS;
    const int g = blk % GROUPS;

    __shared__ unsigned int lh[NBINS];
    for (int i = threadIdx.x; i < NBINS; i += 256) lh[i] = 0;
    __syncthreads();

    float s = 0.f, ss = 0.f;
    for (int bb = 0; bb < BPG; ++bb) {
        const int b = g * BPG + bb;
        const float4* p = (const float4*)(x + (size_t)(b * CCH + c) * HW);
        for (int i = threadIdx.x; i < HW / 4; i += 256) {
            float4 v = p[i];
            float e[4] = {v.x, v.y, v.z, v.w};
#pragma unroll
            for (int j = 0; j < 4; ++j) {
                float vv = e[j];
                s += vv;
                ss = fmaf(vv, vv, ss);
                int bin = (int)fmaf(vv, 128.f, 1024.f);  // (v+8)*NBINS/16
                bin = bin < 0 ? 0 : (bin > NBINS - 1 ? NBINS - 1 : bin);
                atomicAdd(&lh[bin], 1u);
            }
        }
    }
    __syncthreads();

    // flush histogram: pack two u16 counts per u32, plain stores (slice owned by this block)
    unsigned int* dst = histp + (size_t)blk * (NBINS / 2);
    for (int i = threadIdx.x; i < NBINS / 2; i += 256) {
        unsigned int lo = lh[2 * i], hi = lh[2 * i + 1];
        dst[i] = lo | (hi << 16);  // per-group counts <= 25088 < 65536
    }

    // block-reduce sum/sumsq, plain store per group
    for (int off = 32; off; off >>= 1) {
        s += __shfl_down(s, off);
        ss += __shfl_down(ss, off);
    }
    __shared__ float ws_s[4], ws_ss[4];
    const int lane = threadIdx.x & 63, wid = threadIdx.x >> 6;
    if (lane == 0) { ws_s[wid] = s; ws_ss[wid] = ss; }
    __syncthreads();
    if (threadIdx.x == 0) {
        sums[blk] = ws_s[0] + ws_s[1] + ws_s[2] + ws_s[3];
        sums[CCH * GROUPS + blk] = ws_ss[0] + ws_ss[1] + ws_ss[2] + ws_ss[3];
    }
}

__global__ __launch_bounds__(256) void rmbn_finalize_a(const unsigned int* __restrict__ histp,
                                                       const float* __restrict__ sums,
                                                       const float* __restrict__ weight,
                                                       const float* __restrict__ bias,
                                                       const float* __restrict__ smean,
                                                       const float* __restrict__ svar,
                                                       float* __restrict__ scale_shift) {
    const int c = blockIdx.x;
    const int t = threadIdx.x;
    __shared__ unsigned int lh[NBINS];
    __shared__ unsigned int chunk[256];

    // sum the 8 group slices (packed u16x2)
    for (int p = t; p < NBINS / 2; p += 256) {
        unsigned int lo = 0, hi = 0;
#pragma unroll
        for (int g = 0; g < GROUPS; ++g) {
            unsigned int v = histp[(size_t)(c * GROUPS + g) * (NBINS / 2) + p];
            lo += v & 0xFFFFu;
            hi += v >> 16;
        }
        lh[2 * p] = lo;
        lh[2 * p + 1] = hi;
    }
    __syncthreads();

    unsigned int cs = 0;
    for (int j = 0; j < 8; ++j) cs += lh[t * 8 + j];
    chunk[t] = cs;
    __syncthreads();

    if (t == 0) {
        const unsigned int target = (NPC - 1) / 2 + 1;  // 1-indexed rank of lower median
        unsigned int cum = 0;
        int ch = 0;
        for (int i = 0; i < 256; ++i) {
            if (cum + chunk[i] >= target) { ch = i; break; }
            cum += chunk[i];
        }
        int bin = ch * 8;
        for (int j = 0; j < 8; ++j) {
            unsigned int hv = lh[ch * 8 + j];
            if (cum + hv >= target) { bin = ch * 8 + j; break; }
            cum += hv;
        }
        const unsigned int cnt = lh[bin];
        const unsigned int r = target - cum;  // 1..cnt
        const float width = 16.f / NBINS;
        const float lo = -8.f + bin * width;
        const float m = lo + width * (((float)r - 0.5f) / (float)cnt);

        float sum = 0.f, sumsq = 0.f;
#pragma unroll
        for (int g = 0; g < GROUPS; ++g) {
            sum += sums[c * GROUPS + g];
            sumsq += sums[CCH * GROUPS + c * GROUPS + g];
        }
        const float n = (float)NPC;
        const float bvar = sumsq / n - 2.f * m * (sum / n) + m * m;
        const float mean = 0.9f * smean[c] + 0.1f * m;
        const float var = 0.9f * svar[c] + 0.1f * bvar;
        const float inv = rsqrtf(var + 1e-5f);
        const float sc = inv * weight[c];
        scale_shift[c] = sc;
        scale_shift[CCH + c] = bias[c] - mean * sc;
    }
}

// ============================ PATH B (fallback) ============================

__global__ __launch_bounds__(256) void rmbn_stats_b(const float* __restrict__ x,
                                                    unsigned int* __restrict__ hist,
                                                    float* __restrict__ sums) {
    const int blk = blockIdx.x;
    const int c = blk / GROUPS;
    const int g = blk % GROUPS;

    __shared__ unsigned int lh[NBINS];
    for (int i = threadIdx.x; i < NBINS; i += 256) lh[i] = 0;
    __syncthreads();

    float s = 0.f, ss = 0.f;
    for (int bb = 0; bb < BPG; ++bb) {
        const int b = g * BPG + bb;
        const float4* p = (const float4*)(x + (size_t)(b * CCH + c) * HW);
        for (int i = threadIdx.x; i < HW / 4; i += 256) {
            float4 v = p[i];
            float e[4] = {v.x, v.y, v.z, v.w};
#pragma unroll
            for (int j = 0; j < 4; ++j) {
                float vv = e[j];
                s += vv;
                ss = fmaf(vv, vv, ss);
                int bin = (int)fmaf(vv, 128.f, 1024.f);
                bin = bin < 0 ? 0 : (bin > NBINS - 1 ? NBINS - 1 : bin);
                atomicAdd(&lh[bin], 1u);
            }
        }
    }
    __syncthreads();

    for (int i = threadIdx.x; i < NBINS; i += 256) {
        unsigned int v = lh[i];
        if (v) atomicAdd(&hist[c * NBINS + i], v);
    }

    for (int off = 32; off; off >>= 1) {
        s += __shfl_down(s, off);
        ss += __shfl_down(ss, off);
    }
    __shared__ float ws_s[4], ws_ss[4];
    const int lane = threadIdx.x & 63, wid = threadIdx.x >> 6;
    if (lane == 0) { ws_s[wid] = s; ws_ss[wid] = ss; }
    __syncthreads();
    if (threadIdx.x == 0) {
        atomicAdd(&sums[c], ws_s[0] + ws_s[1] + ws_s[2] + ws_s[3]);
        atomicAdd(&sums[CCH + c], ws_ss[0] + ws_ss[1] + ws_ss[2] + ws_ss[3]);
    }
}

__global__ __launch_bounds__(256) void rmbn_finalize_b(const unsigned int* __restrict__ hist,
                                                       const float* __restrict__ sums,
                                                       const float* __restrict__ weight,
                                                       const float* __restrict__ bias,
                                                       const float* __restrict__ smean,
                                                       const float* __restrict__ svar,
                                                       float* __restrict__ scale_shift) {
    const int c = blockIdx.x;
    const int t = threadIdx.x;
    __shared__ unsigned int lh[NBINS];
    __shared__ unsigned int chunk[256];

    const unsigned int* h = hist + c * NBINS;
    for (int j = 0; j < NBINS / 256; ++j) lh[t + 256 * j] = h[t + 256 * j];
    __syncthreads();
    unsigned int cs = 0;
    for (int j = 0; j < 8; ++j) cs += lh[t * 8 + j];
    chunk[t] = cs;
    __syncthreads();

    if (t == 0) {
        const unsigned int target = (NPC - 1) / 2 + 1;
        unsigned int cum = 0;
        int ch = 0;
        for (int i = 0; i < 256; ++i) {
            if (cum + chunk[i] >= target) { ch = i; break; }
            cum += chunk[i];
        }
        int bin = ch * 8;
        for (int j = 0; j < 8; ++j) {
            unsigned int hv = lh[ch * 8 + j];
            if (cum + hv >= target) { bin = ch * 8 + j; break; }
            cum += hv;
        }
        const unsigned int cnt = lh[bin];
        const unsigned int r = target - cum;
        const float width = 16.f / NBINS;
        const float lo = -8.f + bin * width;
        const float m = lo + width * (((float)r - 0.5f) / (float)cnt);

        const float n = (float)NPC;
        const float sum = sums[c], sumsq = sums[CCH + c];
        const float bvar = sumsq / n - 2.f * m * (sum / n) + m * m;
        const float mean = 0.9f * smean[c] + 0.1f * m;
        const float var = 0.9f * svar[c] + 0.1f * bvar;
        const float inv = rsqrtf(var + 1e-5f);
        const float sc = inv * weight[c];
        scale_shift[c] = sc;
        scale_shift[CCH + c] = bias[c] - mean * sc;
    }
}

// ============================ norm pass (shared) ============================

__global__ __launch_bounds__(256) void rmbn_norm(const float* __restrict__ x,
                                                 const float* __restrict__ ss,
                                                 float* __restrict__ out) {
    const int blk = blockIdx.x;  // B*C blocks, one (b,c) slab each
    const int c = blk % CCH;
    const float sc = ss[c];
    const float sh = ss[CCH + c];
    const size_t base = (size_t)blk * HW;
    const f4v* px = (const f4v*)(x + base);
    f4v* po = (f4v*)(out + base);
    for (int i = threadIdx.x; i < HW / 4; i += 256) {
        f4v v = px[i];
        f4v r;
        r.x = fmaf(v.x, sc, sh);
        r.y = fmaf(v.y, sc, sh);
        r.z = fmaf(v.z, sc, sh);
        r.w = fmaf(v.w, sc, sh);
        // non-temporal: keep x resident in L3 instead of out
        __builtin_nontemporal_store(r, &po[i]);
    }
}

extern "C" void kernel_launch(void* const* d_in, const int* in_sizes, int n_in,
                              void* d_out, int out_size, void* d_ws, size_t ws_size,
                              hipStream_t stream) {
    const float* x = (const float*)d_in[0];
    const float* weight = (const float*)d_in[1];
    const float* bias = (const float*)d_in[2];
    const float* smean = (const float*)d_in[3];
    const float* svar = (const float*)d_in[4];
    float* out = (float*)d_out;
    unsigned char* ws = (unsigned char*)d_ws;

    if (ws_size >= (size_t)NEEDA) {
        unsigned int* histp = (unsigned int*)ws;
        float* sums = (float*)(ws + SUMSA_OFF);
        float* scsh = (float*)(ws + SCSHA_OFF);
        rmbn_stats_a<<<CCH * GROUPS, 256, 0, stream>>>(x, histp, sums);
        rmbn_finalize_a<<<CCH, 256, 0, stream>>>(histp, sums, weight, bias, smean, svar, scsh);
        rmbn_norm<<<BATCH * CCH, 256, 0, stream>>>(x, scsh, out);
    } else {
        unsigned int* hist = (unsigned int*)ws;
        float* sums = (float*)(ws + SUMSB_OFF);
        float* scsh = (float*)(ws + SCSHB_OFF);
        hipMemsetAsync(d_ws, 0, ZEROB_BYTES, stream);
        rmbn_stats_b<<<CCH * GROUPS, 256, 0, stream>>>(x, hist, sums);
        rmbn_finalize_b<<<CCH, 256, 0, stream>>>(hist, sums, weight, bias, smean, svar, scsh);
        rmbn_norm<<<BATCH * CCH, 256, 0, stream>>>(x, scsh, out);
    }
}